// Round 3
// baseline (158.875 us; speedup 1.0000x reference)
//
#include <hip/hip_runtime.h>

#define H 256
#define NB 2048
#define BATCH 8
#define NSPLIT 8
#define KSPAN (NB / NSPLIT)   // 256 keys per split

typedef unsigned short u16;
using bf16x8 = __attribute__((ext_vector_type(8))) __bf16;
using f32x4  = __attribute__((ext_vector_type(4))) float;

__device__ __forceinline__ u16 f2bf(float f) {
    union { float f; unsigned u; } v; v.f = f;
    unsigned r = v.u + 0x7fffu + ((v.u >> 16) & 1u);  // RNE
    return (u16)(r >> 16);
}

// ---- weight prep (one block per output row f):
//   aT[f][e] = (sum_d Wq[e][d] Wk[f][d]) / 16   (bf16, B-layout for T = x@A')
//   wvw[f]   = sum_d Wv[f][d] Ww[d]             (fp32)
//   kbv[f]   = sum_d Wk[f][d] bq[d]             (fp32)
__global__ __launch_bounds__(256) void prep_kernel(
        const float* __restrict__ Wq, const float* __restrict__ Wk,
        const float* __restrict__ Wv, const float* __restrict__ Ww,
        const float* __restrict__ bq,
        u16* __restrict__ aT, float* __restrict__ wvw, float* __restrict__ kbv) {
    int f = blockIdx.x, t = threadIdx.x;
    __shared__ float wkf[H];
    __shared__ float redp[4], redr[4];
    float wkval = Wk[f * H + t];
    wkf[t] = wkval;
    float p = Wv[f * H + t] * Ww[t];
    float r = wkval * bq[t];
    __syncthreads();
    float s = 0.f;
    #pragma unroll 8
    for (int d = 0; d < H; ++d) s += Wq[t * H + d] * wkf[d];
    aT[f * H + t] = f2bf(s * 0.0625f);
    for (int o = 32; o; o >>= 1) { p += __shfl_xor(p, o); r += __shfl_xor(r, o); }
    int w = t >> 6, lane = t & 63;
    if (lane == 0) { redp[w] = p; redr[w] = r; }
    __syncthreads();
    if (t == 0) {
        wvw[f] = redp[0] + redp[1] + redp[2] + redp[3];
        kbv[f] = redr[0] + redr[1] + redr[2] + redr[3];
    }
}

// ---- x -> bf16; per-row: u = x·wvw + bv·Ww, d = (x·kbv)/16, e = exp(d);
//      store ue = e*u, ee = e.  One wave per row. ----
__global__ __launch_bounds__(256) void cvtu_kernel(
        const float* __restrict__ x, const float* __restrict__ wvw,
        const float* __restrict__ kbv, const float* __restrict__ bv,
        const float* __restrict__ Ww,
        u16* __restrict__ xbf, float* __restrict__ ue, float* __restrict__ ee) {
    int lane = threadIdx.x & 63;
    int row  = blockIdx.x * 4 + (threadIdx.x >> 6);
    float4 xv = *(const float4*)(x + row * H + lane * 4);
    ushort4 o;
    o.x = f2bf(xv.x); o.y = f2bf(xv.y); o.z = f2bf(xv.z); o.w = f2bf(xv.w);
    *(ushort4*)(xbf + row * H + lane * 4) = o;
    float4 wv = *(const float4*)(wvw + lane * 4);
    float s = xv.x * wv.x + xv.y * wv.y + xv.z * wv.z + xv.w * wv.w;
    float4 kv = *(const float4*)(kbv + lane * 4);
    float d = xv.x * kv.x + xv.y * kv.y + xv.z * kv.z + xv.w * kv.w;
    float4 bvv = *(const float4*)(bv + lane * 4);
    float4 www = *(const float4*)(Ww + lane * 4);
    float c = bvv.x * www.x + bvv.y * www.y + bvv.z * www.z + bvv.w * www.w;
    for (int o2 = 32; o2; o2 >>= 1) {
        s += __shfl_xor(s, o2); d += __shfl_xor(d, o2); c += __shfl_xor(c, o2);
    }
    if (lane == 0) {
        float e = __expf(d * 0.0625f);
        ue[row] = e * (s + c);
        ee[row] = e;
    }
}

// ---- T = xbf @ aT  (bf16 out, MFMA 16x16x32, M=2 subtiles per wave) ----
__global__ __launch_bounds__(256) void projT_kernel(
        const u16* __restrict__ xbf, const u16* __restrict__ aT,
        u16* __restrict__ T) {
    __shared__ u16 bt[64 * 264];
    int tid = threadIdx.x;
    int mb = blockIdx.x * 128, nb = blockIdx.y * 64;

    for (int it = 0; it < 8; ++it) {
        int c = it * 256 + tid;
        int row = c >> 5, col = (c & 31) * 8;
        *(uint4*)&bt[row * 264 + col] = *(const uint4*)(aT + (nb + row) * H + col);
    }
    __syncthreads();

    int w = tid >> 6, lane = tid & 63;
    int l15 = lane & 15, quad = lane >> 4;

    bf16x8 a[2][8];
    for (int mi = 0; mi < 2; ++mi) {
        const u16* abase = xbf + (mb + w * 32 + mi * 16 + l15) * H + quad * 8;
        for (int ks = 0; ks < 8; ++ks) a[mi][ks] = *(const bf16x8*)(abase + ks * 32);
    }

    f32x4 acc[2][4] = {};
    for (int ks = 0; ks < 8; ++ks)
        for (int t = 0; t < 4; ++t) {
            bf16x8 b = *(const bf16x8*)&bt[(t * 16 + l15) * 264 + ks * 32 + quad * 8];
            acc[0][t] = __builtin_amdgcn_mfma_f32_16x16x32_bf16(a[0][ks], b, acc[0][t], 0, 0, 0);
            acc[1][t] = __builtin_amdgcn_mfma_f32_16x16x32_bf16(a[1][ks], b, acc[1][t], 0, 0, 0);
        }

    for (int mi = 0; mi < 2; ++mi) {
        int m = mb + w * 32 + mi * 16 + quad * 4;
        for (int t = 0; t < 4; ++t) {
            int n = nb + t * 16 + l15;
            for (int r = 0; r < 4; ++r)
                T[(m + r) * H + n] = f2bf(acc[mi][t][r]);
        }
    }
}

// ---- attention: logit(n,m) = T[n]·x[m]; num += e^logit·e_m·u_m, den += e^logit·e_m.
//      K-split, 128 q-rows per block, M=2 subtiles per wave. ----
__global__ __launch_bounds__(256) void attn_kernel(
        const u16* __restrict__ T, const u16* __restrict__ xbf,
        const float* __restrict__ ue, const float* __restrict__ ee,
        float* __restrict__ pnum, float* __restrict__ pden) {
    __shared__ u16 kt[64 * 264];
    __shared__ float utile[64], etile[64];
    int tid = threadIdx.x;
    int b = blockIdx.y, qb = blockIdx.x * 128, sp = blockIdx.z;
    int w = tid >> 6, lane = tid & 63, l15 = lane & 15, quad = lane >> 4;

    bf16x8 aq[2][8];
    for (int mi = 0; mi < 2; ++mi) {
        const u16* qbase = T + (size_t)(b * NB + qb + w * 32 + mi * 16 + l15) * H + quad * 8;
        for (int ks = 0; ks < 8; ++ks) aq[mi][ks] = *(const bf16x8*)(qbase + ks * 32);
    }

    float ls[2][4] = {}, as_[2][4] = {};

    const int kb0 = sp * KSPAN;
    for (int kb = kb0; kb < kb0 + KSPAN; kb += 64) {
        const u16* ksrc = xbf + (size_t)(b * NB + kb) * H;
        for (int it = 0; it < 8; ++it) {
            int c = it * 256 + tid;
            int row = c >> 5, col = (c & 31) * 8;
            *(uint4*)&kt[row * 264 + col] = *(const uint4*)(ksrc + row * H + col);
        }
        if (tid < 64) utile[tid] = ue[b * NB + kb + tid];
        else if (tid < 128) etile[tid - 64] = ee[b * NB + kb + (tid - 64)];
        __syncthreads();

        f32x4 acc[2][4] = {};
        for (int ks = 0; ks < 8; ++ks)
            for (int t = 0; t < 4; ++t) {
                bf16x8 bfr = *(const bf16x8*)&kt[(t * 16 + l15) * 264 + ks * 32 + quad * 8];
                acc[0][t] = __builtin_amdgcn_mfma_f32_16x16x32_bf16(aq[0][ks], bfr, acc[0][t], 0, 0, 0);
                acc[1][t] = __builtin_amdgcn_mfma_f32_16x16x32_bf16(aq[1][ks], bfr, acc[1][t], 0, 0, 0);
            }

        float uv[4], ev[4];
        for (int t = 0; t < 4; ++t) { uv[t] = utile[t * 16 + l15]; ev[t] = etile[t * 16 + l15]; }

        for (int mi = 0; mi < 2; ++mi)
            for (int r = 0; r < 4; ++r) {
                float p0 = __expf(acc[mi][0][r]), p1 = __expf(acc[mi][1][r]);
                float p2 = __expf(acc[mi][2][r]), p3 = __expf(acc[mi][3][r]);
                ls[mi][r]  += (p0 * ev[0] + p1 * ev[1]) + (p2 * ev[2] + p3 * ev[3]);
                as_[mi][r] += (p0 * uv[0] + p1 * uv[1]) + (p2 * uv[2] + p3 * uv[3]);
            }
        __syncthreads();
    }

    for (int mi = 0; mi < 2; ++mi)
        for (int r = 0; r < 4; ++r)
            for (int o = 1; o < 16; o <<= 1) {
                ls[mi][r]  += __shfl_xor(ls[mi][r], o);
                as_[mi][r] += __shfl_xor(as_[mi][r], o);
            }

    if (l15 == 0) {
        for (int mi = 0; mi < 2; ++mi) {
            size_t base = (size_t)(sp * BATCH + b) * NB + qb + w * 32 + mi * 16 + quad * 4;
            for (int r = 0; r < 4; ++r) {
                pnum[base + r] = as_[mi][r];
                pden[base + r] = ls[mi][r];
            }
        }
    }
}

// ---- combine K-splits: out = sum(num)/sum(den) + bw ----
__global__ __launch_bounds__(256) void finalize_kernel(
        const float* __restrict__ pnum, const float* __restrict__ pden,
        const float* __restrict__ bw, float* __restrict__ out) {
    int i = blockIdx.x * 256 + threadIdx.x;   // i = b*NB + n
    float num = 0.f, den = 0.f;
    for (int sp = 0; sp < NSPLIT; ++sp) {
        num += pnum[sp * (BATCH * NB) + i];
        den += pden[sp * (BATCH * NB) + i];
    }
    out[i] = num / den + bw[0];
}

extern "C" void kernel_launch(void* const* d_in, const int* in_sizes, int n_in,
                              void* d_out, int out_size, void* d_ws, size_t ws_size,
                              hipStream_t stream) {
    (void)in_sizes; (void)n_in; (void)out_size; (void)ws_size;
    const float* x  = (const float*)d_in[0];
    const float* Wq = (const float*)d_in[1];
    const float* bq = (const float*)d_in[2];
    const float* Wk = (const float*)d_in[3];
    const float* bk = (const float*)d_in[4];  (void)bk;  // cancels in softmax
    const float* Wv = (const float*)d_in[5];
    const float* bv = (const float*)d_in[6];
    const float* Ww = (const float*)d_in[7];
    const float* bw = (const float*)d_in[8];
    float* out = (float*)d_out;

    u16* xbf = (u16*)d_ws;                     // 4194304 u16 (8 MB)
    u16* Tbf = xbf + 4194304;                  // 4194304 u16 (8 MB)
    u16* aT  = Tbf + 4194304;                  // 65536 u16
    float* wvw = (float*)(aT + 65536);         // 256 f32
    float* kbv = wvw + 256;                    // 256 f32
    float* ue  = kbv + 256;                    // 16384 f32
    float* ee  = ue + 16384;                   // 16384 f32
    float* pnum = ee + 16384;                  // NSPLIT*16384 f32
    float* pden = pnum + NSPLIT * BATCH * NB;  // NSPLIT*16384 f32

    hipLaunchKernelGGL(prep_kernel, dim3(256), dim3(256), 0, stream,
                       Wq, Wk, Wv, Ww, bq, aT, wvw, kbv);
    hipLaunchKernelGGL(cvtu_kernel, dim3(4096), dim3(256), 0, stream,
                       x, wvw, kbv, bv, Ww, xbf, ue, ee);
    hipLaunchKernelGGL(projT_kernel, dim3(128, 4), dim3(256), 0, stream,
                       xbf, aT, Tbf);
    hipLaunchKernelGGL(attn_kernel, dim3(16, 8, NSPLIT), dim3(256), 0, stream,
                       Tbf, xbf, ue, ee, pnum, pden);
    hipLaunchKernelGGL(finalize_kernel, dim3(64), dim3(256), 0, stream,
                       pnum, pden, bw, out);
}

// Round 4
// 148.779 us; speedup vs baseline: 1.0679x; 1.0679x over previous
//
#include <hip/hip_runtime.h>

#define H 256
#define NB 2048
#define BATCH 8
#define NSPLIT 8
#define KSPAN (NB / NSPLIT)   // 256 keys per split

typedef unsigned short u16;
using bf16x8 = __attribute__((ext_vector_type(8))) __bf16;
using f32x4  = __attribute__((ext_vector_type(4))) float;

typedef const __attribute__((address_space(1))) void gv_t;
typedef __attribute__((address_space(3))) void lv_t;

// async 16B-per-lane global->LDS: lds dst is wave-uniform base, lane i lands at base+16*i
__device__ __forceinline__ void gl_lds16(const void* g, void* l) {
    __builtin_amdgcn_global_load_lds((gv_t*)g, (lv_t*)l, 16, 0, 0);
}

#define MFMA(a, b, c) __builtin_amdgcn_mfma_f32_16x16x32_bf16(a, b, c, 0, 0, 0)

__device__ __forceinline__ u16 f2bf(float f) {
    union { float f; unsigned u; } v; v.f = f;
    unsigned r = v.u + 0x7fffu + ((v.u >> 16) & 1u);  // RNE
    return (u16)(r >> 16);
}

// ---- weight prep (one block per output row f):
//   aT[f][e] = (sum_d Wq[e][d] Wk[f][d]) / 16   (bf16, B-layout for T = x@A')
//   wvw[f]   = sum_d Wv[f][d] Ww[d]             (fp32)
//   kbv[f]   = sum_d Wk[f][d] bq[d]             (fp32)
__global__ __launch_bounds__(256) void prep_kernel(
        const float* __restrict__ Wq, const float* __restrict__ Wk,
        const float* __restrict__ Wv, const float* __restrict__ Ww,
        const float* __restrict__ bq,
        u16* __restrict__ aT, float* __restrict__ wvw, float* __restrict__ kbv) {
    int f = blockIdx.x, t = threadIdx.x;
    __shared__ float wkf[H];
    __shared__ float redp[4], redr[4];
    float wkval = Wk[f * H + t];
    wkf[t] = wkval;
    float p = Wv[f * H + t] * Ww[t];
    float r = wkval * bq[t];
    __syncthreads();
    float s = 0.f;
    #pragma unroll 8
    for (int d = 0; d < H; ++d) s += Wq[t * H + d] * wkf[d];
    aT[f * H + t] = f2bf(s * 0.0625f);
    for (int o = 32; o; o >>= 1) { p += __shfl_xor(p, o); r += __shfl_xor(r, o); }
    int w = t >> 6, lane = t & 63;
    if (lane == 0) { redp[w] = p; redr[w] = r; }
    __syncthreads();
    if (t == 0) {
        wvw[f] = redp[0] + redp[1] + redp[2] + redp[3];
        kbv[f] = redr[0] + redr[1] + redr[2] + redr[3];
    }
}

// ---- x -> bf16; per-row: u = x·wvw + bv·Ww, d = (x·kbv)/16, e = exp(d);
//      store ue = e*u, ee = e.  One wave per row. ----
__global__ __launch_bounds__(256) void cvtu_kernel(
        const float* __restrict__ x, const float* __restrict__ wvw,
        const float* __restrict__ kbv, const float* __restrict__ bv,
        const float* __restrict__ Ww,
        u16* __restrict__ xbf, float* __restrict__ ue, float* __restrict__ ee) {
    int lane = threadIdx.x & 63;
    int row  = blockIdx.x * 4 + (threadIdx.x >> 6);
    float4 xv = *(const float4*)(x + row * H + lane * 4);
    ushort4 o;
    o.x = f2bf(xv.x); o.y = f2bf(xv.y); o.z = f2bf(xv.z); o.w = f2bf(xv.w);
    *(ushort4*)(xbf + row * H + lane * 4) = o;
    float4 wv = *(const float4*)(wvw + lane * 4);
    float s = xv.x * wv.x + xv.y * wv.y + xv.z * wv.z + xv.w * wv.w;
    float4 kv = *(const float4*)(kbv + lane * 4);
    float d = xv.x * kv.x + xv.y * kv.y + xv.z * kv.z + xv.w * kv.w;
    float4 bvv = *(const float4*)(bv + lane * 4);
    float4 www = *(const float4*)(Ww + lane * 4);
    float c = bvv.x * www.x + bvv.y * www.y + bvv.z * www.z + bvv.w * www.w;
    for (int o2 = 32; o2; o2 >>= 1) {
        s += __shfl_xor(s, o2); d += __shfl_xor(d, o2); c += __shfl_xor(c, o2);
    }
    if (lane == 0) {
        float e = __expf(d * 0.0625f);
        ue[row] = e * (s + c);
        ee[row] = e;
    }
}

// ---- T = xbf @ aT  (bf16 out, MFMA 16x16x32, M=2 subtiles per wave).
//      aT tile staged async into fragment-major LDS: chunk (t*8+ks)*64+lane, 16B each. ----
__global__ __launch_bounds__(256) void projT_kernel(
        const u16* __restrict__ xbf, const u16* __restrict__ aT,
        u16* __restrict__ T) {
    __shared__ u16 bt[16384];   // 32KB fragment-major
    int tid = threadIdx.x;
    int mb = blockIdx.x * 128, nb = blockIdx.y * 64;
    int w = tid >> 6, lane = tid & 63;
    int l15 = lane & 15, quad = lane >> 4;

    {   // wave w stages t=w, ks=0..7
        const u16* gsrc = aT + (nb + w * 16 + l15) * H + quad * 8;
        for (int ks = 0; ks < 8; ++ks)
            gl_lds16(gsrc + ks * 32, bt + (w * 8 + ks) * 512);
    }

    bf16x8 a[2][8];
    for (int mi = 0; mi < 2; ++mi) {
        const u16* abase = xbf + (mb + w * 32 + mi * 16 + l15) * H + quad * 8;
        for (int ks = 0; ks < 8; ++ks) a[mi][ks] = *(const bf16x8*)(abase + ks * 32);
    }
    __syncthreads();

    f32x4 acc[2][4] = {};
    for (int ks = 0; ks < 8; ++ks)
        for (int t = 0; t < 4; ++t) {
            bf16x8 b = *(const bf16x8*)(bt + ((t * 8 + ks) * 64 + lane) * 8);
            acc[0][t] = MFMA(a[0][ks], b, acc[0][t]);
            acc[1][t] = MFMA(a[1][ks], b, acc[1][t]);
        }

    for (int mi = 0; mi < 2; ++mi) {
        int m = mb + w * 32 + mi * 16 + quad * 4;
        for (int t = 0; t < 4; ++t) {
            int n = nb + t * 16 + l15;
            for (int r = 0; r < 4; ++r)
                T[(m + r) * H + n] = f2bf(acc[mi][t][r]);
        }
    }
}

// ---- attention: logit(n,m) = T[n]·x[m]; num += e^logit·(e·u)_m, den += e^logit·e_m.
//      128 q-rows/block, M=2 per wave; K-tile (64 keys) staged async fragment-major.
//      A-fragments re-read from L2 per tile in two 32-reg halves to stay under the
//      128-VGPR occupancy cliff (m69: waves/SIMD halve at 128). ----
__global__ __launch_bounds__(256, 4) void attn_kernel(
        const u16* __restrict__ T, const u16* __restrict__ xbf,
        const float* __restrict__ ue, const float* __restrict__ ee,
        float* __restrict__ pnum, float* __restrict__ pden) {
    __shared__ u16 kt[16384];   // 32KB fragment-major: chunk (t*8+ks)*64+lane
    __shared__ float utile[64], etile[64];
    int tid = threadIdx.x;
    int b = blockIdx.y, qb = blockIdx.x * 128, sp = blockIdx.z;
    int w = tid >> 6, lane = tid & 63, l15 = lane & 15, quad = lane >> 4;

    const u16* qb0 = T + (size_t)(b * NB + qb + w * 32 + l15) * H + quad * 8;
    float ls[2][4] = {}, as_[2][4] = {};

    const int kb0 = sp * KSPAN;
    #pragma unroll 1
    for (int kb = kb0; kb < kb0 + KSPAN; kb += 64) {
        const u16* ksrc = xbf + (size_t)(b * NB + kb) * H;
        {   // wave w stages t=w, ks=0..7 (64x16B per call, lds dst wave-uniform)
            const u16* gsrc = ksrc + (w * 16 + l15) * H + quad * 8;
            for (int ks = 0; ks < 8; ++ks)
                gl_lds16(gsrc + ks * 32, kt + (w * 8 + ks) * 512);
        }
        if (tid < 64) utile[tid] = ue[b * NB + kb + tid];
        else if (tid < 128) etile[tid - 64] = ee[b * NB + kb + (tid - 64)];
        __syncthreads();

        f32x4 acc[2][4] = {};
        #pragma unroll 1
        for (int half = 0; half < 2; ++half) {
            bf16x8 aq[2][4];
            for (int mi = 0; mi < 2; ++mi)
                for (int kk = 0; kk < 4; ++kk)
                    aq[mi][kk] = *(const bf16x8*)(qb0 + mi * 16 * H + (half * 4 + kk) * 32);
            for (int kk = 0; kk < 4; ++kk) {
                int ks = half * 4 + kk;
                for (int t = 0; t < 4; ++t) {
                    bf16x8 bfr = *(const bf16x8*)(kt + ((t * 8 + ks) * 64 + lane) * 8);
                    acc[0][t] = MFMA(aq[0][kk], bfr, acc[0][t]);
                    acc[1][t] = MFMA(aq[1][kk], bfr, acc[1][t]);
                }
            }
        }

        float uv[4], ev[4];
        for (int t = 0; t < 4; ++t) { uv[t] = utile[t * 16 + l15]; ev[t] = etile[t * 16 + l15]; }

        for (int mi = 0; mi < 2; ++mi)
            for (int r = 0; r < 4; ++r) {
                float p0 = __expf(acc[mi][0][r]), p1 = __expf(acc[mi][1][r]);
                float p2 = __expf(acc[mi][2][r]), p3 = __expf(acc[mi][3][r]);
                ls[mi][r]  += (p0 * ev[0] + p1 * ev[1]) + (p2 * ev[2] + p3 * ev[3]);
                as_[mi][r] += (p0 * uv[0] + p1 * uv[1]) + (p2 * uv[2] + p3 * uv[3]);
            }
        __syncthreads();
    }

    for (int mi = 0; mi < 2; ++mi)
        for (int r = 0; r < 4; ++r)
            for (int o = 1; o < 16; o <<= 1) {
                ls[mi][r]  += __shfl_xor(ls[mi][r], o);
                as_[mi][r] += __shfl_xor(as_[mi][r], o);
            }

    if (l15 == 0) {
        for (int mi = 0; mi < 2; ++mi) {
            size_t base = (size_t)(sp * BATCH + b) * NB + qb + w * 32 + mi * 16 + quad * 4;
            for (int r = 0; r < 4; ++r) {
                pnum[base + r] = as_[mi][r];
                pden[base + r] = ls[mi][r];
            }
        }
    }
}

// ---- combine K-splits: out = sum(num)/sum(den) + bw ----
__global__ __launch_bounds__(256) void finalize_kernel(
        const float* __restrict__ pnum, const float* __restrict__ pden,
        const float* __restrict__ bw, float* __restrict__ out) {
    int i = blockIdx.x * 256 + threadIdx.x;   // i = b*NB + n
    float num = 0.f, den = 0.f;
    for (int sp = 0; sp < NSPLIT; ++sp) {
        num += pnum[sp * (BATCH * NB) + i];
        den += pden[sp * (BATCH * NB) + i];
    }
    out[i] = num / den + bw[0];
}

extern "C" void kernel_launch(void* const* d_in, const int* in_sizes, int n_in,
                              void* d_out, int out_size, void* d_ws, size_t ws_size,
                              hipStream_t stream) {
    (void)in_sizes; (void)n_in; (void)out_size; (void)ws_size;
    const float* x  = (const float*)d_in[0];
    const float* Wq = (const float*)d_in[1];
    const float* bq = (const float*)d_in[2];
    const float* Wk = (const float*)d_in[3];
    const float* bk = (const float*)d_in[4];  (void)bk;  // cancels in softmax
    const float* Wv = (const float*)d_in[5];
    const float* bv = (const float*)d_in[6];
    const float* Ww = (const float*)d_in[7];
    const float* bw = (const float*)d_in[8];
    float* out = (float*)d_out;

    u16* xbf = (u16*)d_ws;                     // 4194304 u16 (8 MB)
    u16* Tbf = xbf + 4194304;                  // 4194304 u16 (8 MB)
    u16* aT  = Tbf + 4194304;                  // 65536 u16
    float* wvw = (float*)(aT + 65536);         // 256 f32
    float* kbv = wvw + 256;                    // 256 f32
    float* ue  = kbv + 256;                    // 16384 f32
    float* ee  = ue + 16384;                   // 16384 f32
    float* pnum = ee + 16384;                  // NSPLIT*16384 f32
    float* pden = pnum + NSPLIT * BATCH * NB;  // NSPLIT*16384 f32

    hipLaunchKernelGGL(prep_kernel, dim3(256), dim3(256), 0, stream,
                       Wq, Wk, Wv, Ww, bq, aT, wvw, kbv);
    hipLaunchKernelGGL(cvtu_kernel, dim3(4096), dim3(256), 0, stream,
                       x, wvw, kbv, bv, Ww, xbf, ue, ee);
    hipLaunchKernelGGL(projT_kernel, dim3(128, 4), dim3(256), 0, stream,
                       xbf, aT, Tbf);
    hipLaunchKernelGGL(attn_kernel, dim3(16, 8, NSPLIT), dim3(256), 0, stream,
                       Tbf, xbf, ue, ee, pnum, pden);
    hipLaunchKernelGGL(finalize_kernel, dim3(64), dim3(256), 0, stream,
                       pnum, pden, bw, out);
}

// Round 5
// 129.057 us; speedup vs baseline: 1.2310x; 1.1528x over previous
//
#include <hip/hip_runtime.h>

#define H 256
#define NB 2048
#define BATCH 8
#define NSPLIT 8
#define KSPAN (NB / NSPLIT)   // 256 keys per split
#define NHALF (KSPAN / 32)    // 8 half-tiles of 32 keys

typedef unsigned short u16;
using bf16x8 = __attribute__((ext_vector_type(8))) __bf16;
using f32x4  = __attribute__((ext_vector_type(4))) float;

typedef const __attribute__((address_space(1))) void gv_t;
typedef __attribute__((address_space(3))) void lv_t;

// async 16B-per-lane global->LDS: lds dst is wave-uniform base, lane i lands at base+16*i
__device__ __forceinline__ void gl_lds16(const void* g, void* l) {
    __builtin_amdgcn_global_load_lds((gv_t*)g, (lv_t*)l, 16, 0, 0);
}

#define MFMA(a, b, c) __builtin_amdgcn_mfma_f32_16x16x32_bf16(a, b, c, 0, 0, 0)

__device__ __forceinline__ u16 f2bf(float f) {
    union { float f; unsigned u; } v; v.f = f;
    unsigned r = v.u + 0x7fffu + ((v.u >> 16) & 1u);  // RNE
    return (u16)(r >> 16);
}

// ---- coalesced weight prep (one block per row f):
//   wqb/wkb = bf16(Wq/Wk) row-major; wvw[f] = Wv[f,:]·Ww; kbv[f] = Wk[f,:]·bq ----
__global__ __launch_bounds__(256) void wprep_kernel(
        const float* __restrict__ Wq, const float* __restrict__ Wk,
        const float* __restrict__ Wv, const float* __restrict__ Ww,
        const float* __restrict__ bq,
        u16* __restrict__ wqb, u16* __restrict__ wkb,
        float* __restrict__ wvw, float* __restrict__ kbv) {
    int f = blockIdx.x, t = threadIdx.x;
    float wq = Wq[f * H + t];
    wqb[f * H + t] = f2bf(wq);
    float wk = Wk[f * H + t];
    wkb[f * H + t] = f2bf(wk);
    float p = Wv[f * H + t] * Ww[t];
    float r = wk * bq[t];
    for (int o = 32; o; o >>= 1) { p += __shfl_xor(p, o); r += __shfl_xor(r, o); }
    __shared__ float redp[4], redr[4];
    int w = t >> 6, lane = t & 63;
    if (lane == 0) { redp[w] = p; redr[w] = r; }
    __syncthreads();
    if (t == 0) {
        wvw[f] = redp[0] + redp[1] + redp[2] + redp[3];
        kbv[f] = redr[0] + redr[1] + redr[2] + redr[3];
    }
}

// ---- x -> bf16; per-row: u = x·wvw + bv·Ww, d = (x·kbv)/16, e = exp(d);
//      store uee[row] = {e*u, e}.  One wave per row. ----
__global__ __launch_bounds__(256) void cvtu_kernel(
        const float* __restrict__ x, const float* __restrict__ wvw,
        const float* __restrict__ kbv, const float* __restrict__ bv,
        const float* __restrict__ Ww,
        u16* __restrict__ xbf, float2* __restrict__ uee) {
    int lane = threadIdx.x & 63;
    int row  = blockIdx.x * 4 + (threadIdx.x >> 6);
    float4 xv = *(const float4*)(x + row * H + lane * 4);
    ushort4 o;
    o.x = f2bf(xv.x); o.y = f2bf(xv.y); o.z = f2bf(xv.z); o.w = f2bf(xv.w);
    *(ushort4*)(xbf + row * H + lane * 4) = o;
    float4 wv = *(const float4*)(wvw + lane * 4);
    float s = xv.x * wv.x + xv.y * wv.y + xv.z * wv.z + xv.w * wv.w;
    float4 kv = *(const float4*)(kbv + lane * 4);
    float d = xv.x * kv.x + xv.y * kv.y + xv.z * kv.z + xv.w * kv.w;
    float4 bvv = *(const float4*)(bv + lane * 4);
    float4 www = *(const float4*)(Ww + lane * 4);
    float c = bvv.x * www.x + bvv.y * www.y + bvv.z * www.z + bvv.w * www.w;
    for (int o2 = 32; o2; o2 >>= 1) {
        s += __shfl_xor(s, o2); d += __shfl_xor(d, o2); c += __shfl_xor(c, o2);
    }
    if (lane == 0) {
        float e = __expf(d * 0.0625f);
        uee[row] = make_float2(e * (s + c), e);
    }
}

// ---- generic C = (A @ B^T) * scale, bf16 in/out, MFMA 16x16x32, M=2/wave.
//      A: Mx256 row-major bf16; B: 256x256 row-major bf16 (N-rows); C: MxN(=256).
//      Used for aT = (Wk@Wq^T)/16 and T = xbf@aT^T(row-major trick: aT is B-layout). ----
__global__ __launch_bounds__(256) void gemm_bt_kernel(
        const u16* __restrict__ A, const u16* __restrict__ B,
        u16* __restrict__ C, float scale) {
    __shared__ u16 bt[16384];   // 32KB fragment-major
    int tid = threadIdx.x;
    int mb = blockIdx.x * 128, nb = blockIdx.y * 64;
    int w = tid >> 6, lane = tid & 63;
    int l15 = lane & 15, quad = lane >> 4;

    {   // wave w stages t=w, ks=0..7
        const u16* gsrc = B + (nb + w * 16 + l15) * H + quad * 8;
        for (int ks = 0; ks < 8; ++ks)
            gl_lds16(gsrc + ks * 32, bt + (w * 8 + ks) * 512);
    }

    bf16x8 a[2][8];
    for (int mi = 0; mi < 2; ++mi) {
        const u16* abase = A + (size_t)(mb + w * 32 + mi * 16 + l15) * H + quad * 8;
        for (int ks = 0; ks < 8; ++ks) a[mi][ks] = *(const bf16x8*)(abase + ks * 32);
    }
    __syncthreads();

    f32x4 acc[2][4] = {};
    for (int ks = 0; ks < 8; ++ks)
        for (int t = 0; t < 4; ++t) {
            bf16x8 b = *(const bf16x8*)(bt + ((t * 8 + ks) * 64 + lane) * 8);
            acc[0][t] = MFMA(a[0][ks], b, acc[0][t]);
            acc[1][t] = MFMA(a[1][ks], b, acc[1][t]);
        }

    for (int mi = 0; mi < 2; ++mi) {
        int m = mb + w * 32 + mi * 16 + quad * 4;
        for (int t = 0; t < 4; ++t) {
            int n = nb + t * 16 + l15;
            for (int r = 0; r < 4; ++r)
                C[(size_t)(m + r) * H + n] = f2bf(acc[mi][t][r] * scale);
        }
    }
}

// ---- attention: logit(n,m) = T[n]·x[m]; num += e^logit·(e·u)_m, den += e^logit·e_m.
//      128 q-rows/block, M=2/wave, aq resident (64 VGPR). K staged in 32-key
//      double-buffered halves: issue stage(h+1) -> compute(h) -> one barrier,
//      so the vmcnt(0) drain lands after the compute (latency hidden). ----
__global__ __launch_bounds__(256, 4) void attn_kernel(
        const u16* __restrict__ T, const u16* __restrict__ xbf,
        const float2* __restrict__ uee,
        float* __restrict__ pnum, float* __restrict__ pden) {
    __shared__ u16 kt[16384];   // 2 x 16KB fragment-major half-tiles
    int tid = threadIdx.x;
    int b = blockIdx.y, qb = blockIdx.x * 128, sp = blockIdx.z;
    int w = tid >> 6, lane = tid & 63, l15 = lane & 15, quad = lane >> 4;

    // resident A fragments: 32 q-rows per wave
    bf16x8 aq[2][8];
    for (int mi = 0; mi < 2; ++mi) {
        const u16* qbase = T + (size_t)(b * NB + qb + w * 32 + mi * 16 + l15) * H + quad * 8;
        for (int ks = 0; ks < 8; ++ks) aq[mi][ks] = *(const bf16x8*)(qbase + ks * 32);
    }

    const u16* xb = xbf + (size_t)b * NB * H;
    const float2* uep = uee + (size_t)b * NB;
    const int kb0 = sp * KSPAN;

    // wave w stages chunks c = w*4 .. w*4+3 of the 16-chunk (t*8+ks) half-tile
    int c0 = w * 4;
    // stage half 0
    {
        const u16* g = xb + (size_t)(kb0 + (c0 >> 3) * 16 + l15) * H + (c0 & 7) * 32 + quad * 8;
        for (int j = 0; j < 4; ++j) {
            int c = c0 + j;
            gl_lds16(xb + (size_t)(kb0 + (c >> 3) * 16 + l15) * H + (c & 7) * 32 + quad * 8,
                     kt + c * 512);
        }
        (void)g;
    }
    __syncthreads();

    float ls[2][4] = {}, as_[2][4] = {};

    #pragma unroll 1
    for (int h = 0; h < NHALF; ++h) {
        int cur = h & 1;
        if (h + 1 < NHALF) {
            int kb32 = kb0 + (h + 1) * 32;
            u16* dst = kt + (cur ^ 1) * 8192;
            for (int j = 0; j < 4; ++j) {
                int c = c0 + j;
                gl_lds16(xb + (size_t)(kb32 + (c >> 3) * 16 + l15) * H + (c & 7) * 32 + quad * 8,
                         dst + c * 512);
            }
        }
        int kb32 = kb0 + h * 32;
        float2 ue0 = uep[kb32 + l15];
        float2 ue1 = uep[kb32 + 16 + l15];

        const u16* ktc = kt + cur * 8192;
        f32x4 acc[2][2] = {};
        for (int ks = 0; ks < 8; ++ks)
            for (int t = 0; t < 2; ++t) {
                bf16x8 bfr = *(const bf16x8*)(ktc + ((t * 8 + ks) * 64 + lane) * 8);
                acc[0][t] = MFMA(aq[0][ks], bfr, acc[0][t]);
                acc[1][t] = MFMA(aq[1][ks], bfr, acc[1][t]);
            }

        for (int mi = 0; mi < 2; ++mi)
            for (int r = 0; r < 4; ++r) {
                float p0 = __expf(acc[mi][0][r]);
                float p1 = __expf(acc[mi][1][r]);
                as_[mi][r] += p0 * ue0.x + p1 * ue1.x;
                ls[mi][r]  += p0 * ue0.y + p1 * ue1.y;
            }
        __syncthreads();
    }

    for (int mi = 0; mi < 2; ++mi)
        for (int r = 0; r < 4; ++r)
            for (int o = 1; o < 16; o <<= 1) {
                ls[mi][r]  += __shfl_xor(ls[mi][r], o);
                as_[mi][r] += __shfl_xor(as_[mi][r], o);
            }

    if (l15 == 0) {
        for (int mi = 0; mi < 2; ++mi) {
            size_t base = (size_t)(sp * BATCH + b) * NB + qb + w * 32 + mi * 16 + quad * 4;
            for (int r = 0; r < 4; ++r) {
                pnum[base + r] = as_[mi][r];
                pden[base + r] = ls[mi][r];
            }
        }
    }
}

// ---- combine K-splits: out = sum(num)/sum(den) + bw ----
__global__ __launch_bounds__(256) void finalize_kernel(
        const float* __restrict__ pnum, const float* __restrict__ pden,
        const float* __restrict__ bw, float* __restrict__ out) {
    int i = blockIdx.x * 256 + threadIdx.x;   // i = b*NB + n
    float num = 0.f, den = 0.f;
    for (int sp = 0; sp < NSPLIT; ++sp) {
        num += pnum[sp * (BATCH * NB) + i];
        den += pden[sp * (BATCH * NB) + i];
    }
    out[i] = num / den + bw[0];
}

extern "C" void kernel_launch(void* const* d_in, const int* in_sizes, int n_in,
                              void* d_out, int out_size, void* d_ws, size_t ws_size,
                              hipStream_t stream) {
    (void)in_sizes; (void)n_in; (void)out_size; (void)ws_size;
    const float* x  = (const float*)d_in[0];
    const float* Wq = (const float*)d_in[1];
    const float* bq = (const float*)d_in[2];
    const float* Wk = (const float*)d_in[3];
    const float* bk = (const float*)d_in[4];  (void)bk;  // cancels in softmax
    const float* Wv = (const float*)d_in[5];
    const float* bv = (const float*)d_in[6];
    const float* Ww = (const float*)d_in[7];
    const float* bw = (const float*)d_in[8];
    float* out = (float*)d_out;

    u16* xbf = (u16*)d_ws;                     // 4194304 u16 (8 MB)
    u16* Tbf = xbf + 4194304;                  // 4194304 u16 (8 MB)
    u16* aTb = Tbf + 4194304;                  // 65536 u16
    u16* wqb = aTb + 65536;                    // 65536 u16
    u16* wkb = wqb + 65536;                    // 65536 u16
    float* wvw = (float*)(wkb + 65536);        // 256 f32
    float* kbv = wvw + 256;                    // 256 f32
    float2* uee = (float2*)(kbv + 256);        // 16384 float2
    float* pnum = (float*)(uee + 16384);       // NSPLIT*16384 f32
    float* pden = pnum + NSPLIT * BATCH * NB;  // NSPLIT*16384 f32

    hipLaunchKernelGGL(wprep_kernel, dim3(256), dim3(256), 0, stream,
                       Wq, Wk, Wv, Ww, bq, wqb, wkb, wvw, kbv);
    // aT[f][e] = (Wk[f,:]·Wq[e,:])/16
    hipLaunchKernelGGL(gemm_bt_kernel, dim3(2, 4), dim3(256), 0, stream,
                       wkb, wqb, aTb, 0.0625f);
    hipLaunchKernelGGL(cvtu_kernel, dim3(4096), dim3(256), 0, stream,
                       x, wvw, kbv, bv, Ww, xbf, uee);
    // T = xbf @ aT^T (aTb rows are B-operand rows)
    hipLaunchKernelGGL(gemm_bt_kernel, dim3(128, 4), dim3(256), 0, stream,
                       xbf, aTb, Tbf, 1.0f);
    hipLaunchKernelGGL(attn_kernel, dim3(16, 8, NSPLIT), dim3(256), 0, stream,
                       Tbf, xbf, uee, pnum, pden);
    hipLaunchKernelGGL(finalize_kernel, dim3(64), dim3(256), 0, stream,
                       pnum, pden, bw, out);
}